// Round 10
// baseline (309.510 us; speedup 1.0000x reference)
//
#include <hip/hip_runtime.h>
#include <math.h>

#define BN_EPS 1e-5f
#define NEG_SLOPE 0.2f

__device__ __forceinline__ float relu_f(float x) { return x > 0.f ? x : 0.f; }
__device__ __forceinline__ float leaky_f(float z) { return z > 0.f ? z : NEG_SLOPE * z; }

// ---------------- conv1 (3->64, 3x3 SAME) fused bias+BN+ReLU+2x2maxpool ----------------
// grid 512 = b(8) x cog(16) x q(4); 256 threads = one pooled position, 4 co
// Also zeroes the closer counters (block 0) — stream-ordered before any use.
__global__ void conv1_pool(const float* __restrict__ img, const float* __restrict__ w,
                           const float* __restrict__ cb, const float* __restrict__ g,
                           const float* __restrict__ bb, const float* __restrict__ m,
                           const float* __restrict__ vv, float* __restrict__ out,
                           int* __restrict__ cnts)
{
    int blk = blockIdx.x;
    int t = threadIdx.x;
    if (blk == 0 && t < 200) cnts[t] = 0;
    int q = blk & 3, cog = (blk >> 2) & 15, b = blk >> 6;
    int x = t & 31, y = (q << 3) + (t >> 5);

    float acc[4][4] = {};
#pragma unroll
    for (int ci = 0; ci < 3; ++ci) {
        const float* ib = img + (b * 3 + ci) * 4096;
        float rv[4][4];
#pragma unroll
        for (int r = 0; r < 4; ++r) {
            int yy = 2 * y - 1 + r;
            bool yok = (unsigned)yy < 64u;
            const float* p = ib + yy * 64 + 2 * x;
            float2 c01 = yok ? *(const float2*)p : make_float2(0.f, 0.f);
            rv[r][1] = c01.x;
            rv[r][2] = c01.y;
            rv[r][0] = (yok && x > 0) ? p[-1] : 0.f;
            rv[r][3] = (yok && x < 31) ? p[2] : 0.f;
        }
#pragma unroll
        for (int j = 0; j < 4; ++j) {
            const float* wj = w + ((cog * 4 + j) * 3 + ci) * 9;
#pragma unroll
            for (int ky = 0; ky < 3; ++ky)
#pragma unroll
                for (int kx = 0; kx < 3; ++kx) {
                    float wvv = wj[ky * 3 + kx];
#pragma unroll
                    for (int py = 0; py < 2; ++py)
#pragma unroll
                        for (int px = 0; px < 2; ++px)
                            acc[j][py * 2 + px] += rv[py + ky][px + kx] * wvv;
                }
        }
    }
#pragma unroll
    for (int j = 0; j < 4; ++j) {
        int co = cog * 4 + j;
        float inv = g[co] / sqrtf(vv[co] + BN_EPS);
        float sh = cb[co] * inv + (bb[co] - m[co] * inv);
        float v0 = relu_f(acc[j][0] * inv + sh);
        float v1 = relu_f(acc[j][1] * inv + sh);
        float v2 = relu_f(acc[j][2] * inv + sh);
        float v3 = relu_f(acc[j][3] * inv + sh);
        out[((b * 64 + co) * 32 + y) * 32 + x] = fmaxf(fmaxf(v0, v1), fmaxf(v2, v3));
    }
}

// ---------------- conv2: 64->128, 3x3 SAME, SPLIT-K over ci (2 ways) ----------------
// grid 1024 = b(8) x cog(32) x half(2) x kz(2); 256 threads; each block reduces 32 ci.
// Partials BLOCK-LINEAR (fully coalesced): plane[kz] at ((bid*256+t)*8), bid=b*64+cog*2+half
__global__ void conv2_split(const float* __restrict__ in, const float* __restrict__ w,
                            float* __restrict__ c2p)
{
    int blk = blockIdx.x;
    int kz = blk & 1, half = (blk >> 1) & 1, cog = (blk >> 2) & 31, b = blk >> 7;
    int t = threadIdx.x;
    int x2p = (t & 15) * 2;
    int y = half * 16 + (t >> 4);
    bool xnz = x2p != 0;
    bool xhi = x2p == 30;
    const float* ibase = in + b * 65536 + kz * 32768;
    int xb = xnz ? x2p - 1 : 0;

    float acc[4][2] = {};

#pragma unroll 2
    for (int ci = 0; ci < 32; ++ci) {
        const float* cb2 = ibase + ci * 1024;
        float rc[3][4];
#pragma unroll
        for (int r = 0; r < 3; ++r) {
            int yy = y - 1 + r;
            bool yok = (unsigned)yy < 32u;
            const float* p = cb2 + yy * 32 + xb;
            float4 f = yok ? *(const float4*)p : make_float4(0.f, 0.f, 0.f, 0.f);
            rc[r][0] = xnz ? f.x : 0.f;
            rc[r][1] = xnz ? f.y : f.x;
            rc[r][2] = xnz ? f.z : f.y;
            float r3 = xnz ? f.w : f.z;
            rc[r][3] = xhi ? 0.f : r3;
        }
#pragma unroll
        for (int j = 0; j < 4; ++j) {
            const float* wj = w + ((cog * 4 + j) * 64 + kz * 32 + ci) * 9;
#pragma unroll
            for (int ky = 0; ky < 3; ++ky)
#pragma unroll
                for (int kx = 0; kx < 3; ++kx) {
                    float wvv = wj[ky * 3 + kx];
                    acc[j][0] += rc[ky][kx] * wvv;
                    acc[j][1] += rc[ky][kx + 1] * wvv;
                }
        }
    }

    float* pp = c2p + (size_t)kz * 1048576;
    int bid = b * 64 + cog * 2 + half;
    size_t base = ((size_t)bid * 256 + t) * 8;
    float4 s0 = {acc[0][0], acc[1][0], acc[2][0], acc[3][0]};
    float4 s1 = {acc[0][1], acc[1][1], acc[2][1], acc[3][1]};
    *(float4*)&pp[base] = s0;
    *(float4*)&pp[base + 4] = s1;
}

// ---------------- gemm1: h1 = relu(BN(plane0+plane1)) @ g1w, conv2-combine FUSED ----------
// A consumed directly from the block-linear conv2 planes — uniform across all blocks.
// grid (256, 4), 256 threads; 32x64 tile, 2x4 micro; score epilogue for m0<1024.
__global__ void gemm1_planes(const float* __restrict__ c2p,
                             const float* __restrict__ cb, const float* __restrict__ g,
                             const float* __restrict__ bb, const float* __restrict__ mbn,
                             const float* __restrict__ vv,
                             const float* __restrict__ B, float* __restrict__ C,
                             const float* __restrict__ asrc, const float* __restrict__ adst,
                             float* __restrict__ sp, float* __restrict__ dp)
{
    __shared__ float As[16][33];
    __shared__ float Bs[16][64];
    __shared__ float invs[128];
    __shared__ float shs[128];
    int t = threadIdx.x;
    if (t < 128) {
        float iv = g[t] / sqrtf(vv[t] + BN_EPS);
        invs[t] = iv;
        shs[t] = cb[t] * iv + (bb[t] - mbn[t] * iv);
    }

    int m0 = blockIdx.x * 32;
    int n0 = blockIdx.y * 64;
    int tx = t & 15, ty = t >> 4;
    int cg = t >> 6, u = t & 63;
    int xp = u >> 2, odd = (u >> 1) & 1, j0 = (u & 1) * 2;
    int node = 2 * xp + odd;
    int kloc = cg * 4 + j0;
    int b = m0 >> 10, y = (m0 >> 5) & 31;
    int half = y >> 4, yy = y & 15;
    size_t base = (size_t)(b * 64 + half) * 2048 + yy * 128 + cg * 4096 + 2 * u;
    const float* p0 = c2p + base;
    const float* p1 = c2p + 1048576 + base;
    __syncthreads();

    float acc[2][4] = {};
    for (int k0 = 0; k0 < 128; k0 += 16) {
        float2 u0 = *(const float2*)&p0[(size_t)k0 * 1024];
        float2 u1 = *(const float2*)&p1[(size_t)k0 * 1024];
        int ch = k0 + kloc;
        float avx = relu_f((u0.x + u1.x) * invs[ch] + shs[ch]);
        float avy = relu_f((u0.y + u1.y) * invs[ch + 1] + shs[ch + 1]);
        float4 bv = *(const float4*)&B[(size_t)(k0 + ty) * 256 + n0 + tx * 4];
        __syncthreads();
        As[kloc][node] = avx;
        As[kloc + 1][node] = avy;
        *(float4*)&Bs[ty][tx * 4] = bv;
        __syncthreads();
#pragma unroll
        for (int kk = 0; kk < 16; ++kk) {
            float a0 = As[kk][ty * 2], a1 = As[kk][ty * 2 + 1];
            float4 b4 = *(const float4*)&Bs[kk][tx * 4];
            acc[0][0] += a0 * b4.x; acc[0][1] += a0 * b4.y;
            acc[0][2] += a0 * b4.z; acc[0][3] += a0 * b4.w;
            acc[1][0] += a1 * b4.x; acc[1][1] += a1 * b4.y;
            acc[1][2] += a1 * b4.z; acc[1][3] += a1 * b4.w;
        }
    }
#pragma unroll
    for (int i = 0; i < 2; ++i) {
        float4 o = {acc[i][0], acc[i][1], acc[i][2], acc[i][3]};
        *(float4*)&C[(size_t)(m0 + ty * 2 + i) * 256 + n0 + tx * 4] = o;
    }

    if (m0 < 1024) {
        float4 as4 = *(const float4*)&asrc[n0 + tx * 4];
        float4 ad4 = *(const float4*)&adst[n0 + tx * 4];
#pragma unroll
        for (int i = 0; i < 2; ++i) {
            float ss = acc[i][0] * as4.x + acc[i][1] * as4.y +
                       acc[i][2] * as4.z + acc[i][3] * as4.w;
            float dd = acc[i][0] * ad4.x + acc[i][1] * ad4.y +
                       acc[i][2] * ad4.z + acc[i][3] * ad4.w;
#pragma unroll
            for (int off = 1; off < 16; off <<= 1) {
                ss += __shfl_xor(ss, off);
                dd += __shfl_xor(dd, off);
            }
            if (tx == 0) {
                sp[blockIdx.y * 1024 + m0 + ty * 2 + i] = ss;
                dp[blockIdx.y * 1024 + m0 + ty * 2 + i] = dd;
            }
        }
    }
}

// ---------------- tiled GEMM (gemm2): 32x64 tile, 256 threads, 2x4 micro ----------------
template <int K, int N, bool SELF, bool SCORE>
__global__ void gemm32(const float* __restrict__ A, const float* __restrict__ Ahi,
                       const float* __restrict__ abias,
                       const float* __restrict__ B, float* __restrict__ C,
                       const float* __restrict__ asrc, const float* __restrict__ adst,
                       float* __restrict__ sp, float* __restrict__ dp)
{
    __shared__ float As[16][33];
    __shared__ float Bs[16][64];
    int t = threadIdx.x;
    int m0 = blockIdx.x * 32;
    int n0 = blockIdx.y * 64;
    int tx = t & 15, ty = t >> 4;
    int am = t >> 3, ak2 = (t & 7) * 2;
    bool hi = SELF && m0 >= 1024;
    const float* Ab = hi ? Ahi : A;
    float acc[2][4] = {};

    for (int k0 = 0; k0 < K; k0 += 16) {
        float2 av = *(const float2*)&Ab[(size_t)(m0 + am) * K + k0 + ak2];
        if (hi) {
            av.x = relu_f(av.x + abias[k0 + ak2]);
            av.y = relu_f(av.y + abias[k0 + ak2 + 1]);
        }
        float4 bv = *(const float4*)&B[(size_t)(k0 + ty) * N + n0 + tx * 4];
        __syncthreads();
        As[ak2][am] = av.x;
        As[ak2 + 1][am] = av.y;
        *(float4*)&Bs[ty][tx * 4] = bv;
        __syncthreads();
#pragma unroll
        for (int kk = 0; kk < 16; ++kk) {
            float a0 = As[kk][ty * 2], a1 = As[kk][ty * 2 + 1];
            float4 b4 = *(const float4*)&Bs[kk][tx * 4];
            acc[0][0] += a0 * b4.x; acc[0][1] += a0 * b4.y;
            acc[0][2] += a0 * b4.z; acc[0][3] += a0 * b4.w;
            acc[1][0] += a1 * b4.x; acc[1][1] += a1 * b4.y;
            acc[1][2] += a1 * b4.z; acc[1][3] += a1 * b4.w;
        }
    }
#pragma unroll
    for (int i = 0; i < 2; ++i) {
        float4 o = {acc[i][0], acc[i][1], acc[i][2], acc[i][3]};
        *(float4*)&C[(size_t)(m0 + ty * 2 + i) * N + n0 + tx * 4] = o;
    }

    if (SCORE && m0 < 1024) {
        float4 as4 = *(const float4*)&asrc[n0 + tx * 4];
        float4 ad4 = *(const float4*)&adst[n0 + tx * 4];
#pragma unroll
        for (int i = 0; i < 2; ++i) {
            float ss = acc[i][0] * as4.x + acc[i][1] * as4.y +
                       acc[i][2] * as4.z + acc[i][3] * as4.w;
            float dd = acc[i][0] * ad4.x + acc[i][1] * ad4.y +
                       acc[i][2] * ad4.z + acc[i][3] * ad4.w;
#pragma unroll
            for (int off = 1; off < 16; off <<= 1) {
                ss += __shfl_xor(ss, off);
                dd += __shfl_xor(dd, off);
            }
            if (tx == 0) {
                sp[blockIdx.y * 1024 + m0 + ty * 2 + i] = ss;
                dp[blockIdx.y * 1024 + m0 + ty * 2 + i] = dd;
            }
        }
    }
}

// ---------------- GAT aggregation split-K GEMM + LAST-ARRIVER COMBINE CLOSER --------------
// C[v,c] = sum_u exp(leaky(s[u]+d[v]) - m[v]) * h[u,c];  m[v] = leaky(smax + d[v])
// Partials to pacc/pden; the last kz-block per (m0,n0) tile (device-scope atomic after
// threadfence — the documented cross-XCD mitigation) combines all KS planes and writes
// outx = relu(sum*rden + bias). Combine order = fixed ks 0..KS-1 (bit-identical to the
// old gat_combine kernel). grid (32, D/64, KS), 256 threads.
template <int D, int KS, int NT>
__global__ void gat_agg_gemm(const float* __restrict__ h, const float* __restrict__ sp,
                             const float* __restrict__ dp, float* __restrict__ pacc,
                             float* __restrict__ pden,
                             const float* __restrict__ bias, float* __restrict__ outx,
                             int* __restrict__ tilecnt)
{
    __shared__ float Ss[1024];
    __shared__ float As[16][33];
    __shared__ float Bs[16][64];
    __shared__ float red[4];
    __shared__ float part[16][32];
    __shared__ int lastf;

    const int CH = 1024 / KS;
    int t = threadIdx.x;
    int m0 = blockIdx.x * 32;
    int n0 = blockIdx.y * 64;
    int kz = blockIdx.z;
    int tx = t & 15, ty = t >> 4;
    int vg2 = tx * 2;

    float4 sa = {0.f, 0.f, 0.f, 0.f};
#pragma unroll
    for (int nt = 0; nt < NT; ++nt) {
        float4 u = *(const float4*)&sp[nt * 1024 + t * 4];
        sa.x += u.x; sa.y += u.y; sa.z += u.z; sa.w += u.w;
    }
    *(float4*)&Ss[t * 4] = sa;
    float lm = fmaxf(fmaxf(sa.x, sa.y), fmaxf(sa.z, sa.w));
#pragma unroll
    for (int off = 1; off < 64; off <<= 1) lm = fmaxf(lm, __shfl_xor(lm, off));
    if ((t & 63) == 0) red[t >> 6] = lm;
    __syncthreads();
    float smax = fmaxf(fmaxf(red[0], red[1]), fmaxf(red[2], red[3]));

    float dv0 = 0.f, dv1 = 0.f;
#pragma unroll
    for (int nt = 0; nt < NT; ++nt) {
        dv0 += dp[nt * 1024 + m0 + vg2];
        dv1 += dp[nt * 1024 + m0 + vg2 + 1];
    }
    float mv0 = leaky_f(smax + dv0), mv1 = leaky_f(smax + dv1);
    float ds0 = 0.f, ds1 = 0.f;
    float acc[2][4] = {};

    for (int k0 = kz * CH; k0 < kz * CH + CH; k0 += 16) {
        float4 bv = *(const float4*)&h[(size_t)(k0 + ty) * D + n0 + tx * 4];
        float su = Ss[k0 + ty];
        float a0 = __expf(leaky_f(su + dv0) - mv0);
        float a1 = __expf(leaky_f(su + dv1) - mv1);
        ds0 += a0; ds1 += a1;
        __syncthreads();
        As[ty][vg2] = a0;
        As[ty][vg2 + 1] = a1;
        *(float4*)&Bs[ty][tx * 4] = bv;
        __syncthreads();
#pragma unroll
        for (int kk = 0; kk < 16; ++kk) {
            float a0m = As[kk][ty * 2], a1m = As[kk][ty * 2 + 1];
            float4 b4 = *(const float4*)&Bs[kk][tx * 4];
            acc[0][0] += a0m * b4.x; acc[0][1] += a0m * b4.y;
            acc[0][2] += a0m * b4.z; acc[0][3] += a0m * b4.w;
            acc[1][0] += a1m * b4.x; acc[1][1] += a1m * b4.y;
            acc[1][2] += a1m * b4.z; acc[1][3] += a1m * b4.w;
        }
    }

    __syncthreads();
    part[ty][vg2] = ds0;
    part[ty][vg2 + 1] = ds1;
    __syncthreads();

#pragma unroll
    for (int i = 0; i < 2; ++i) {
        float4 o = {acc[i][0], acc[i][1], acc[i][2], acc[i][3]};
        *(float4*)&pacc[((size_t)kz * 1024 + m0 + ty * 2 + i) * D + n0 + tx * 4] = o;
    }
    if (t < 32) {
        float den = 0.f;
#pragma unroll
        for (int u = 0; u < 16; ++u) den += part[u][t];
        pden[kz * 1024 + m0 + t] = den;
    }

    // ---- closer: last kz-block for this (m0,n0) combines planes -> outx ----
    __threadfence();                 // release: all this block's pacc/pden writes
    __syncthreads();                 // all threads' fences precede the signal
    if (t == 0) lastf = (atomicAdd(&tilecnt[blockIdx.x * (D / 64) + blockIdx.y], 1) == KS - 1);
    __syncthreads();
    if (lastf) {
        __threadfence();             // acquire: other blocks' writes now visible
#pragma unroll
        for (int it = 0; it < 2; ++it) {
            int idx = it * 256 + t;          // [0,512): 32 rows x 16 col-quads
            int r = idx >> 4, c4 = idx & 15;
            int v = m0 + r;
            float4 a = {0.f, 0.f, 0.f, 0.f};
            float den = 0.f;
#pragma unroll
            for (int ks = 0; ks < KS; ++ks) {
                float4 p = *(const float4*)&pacc[((size_t)(ks * 1024 + v)) * D + n0 + c4 * 4];
                a.x += p.x; a.y += p.y; a.z += p.z; a.w += p.w;
                den += pden[ks * 1024 + v];
            }
            float rd = 1.f / den;
            float4 bz = ((const float4*)bias)[(n0 >> 2) + c4];
            float4 o = {relu_f(a.x * rd + bz.x), relu_f(a.y * rd + bz.y),
                        relu_f(a.z * rd + bz.z), relu_f(a.w * rd + bz.w)};
            *(float4*)&outx[(size_t)v * D + n0 + c4 * 4] = o;
        }
    }
}

// ---------------- mean-pool + fused self-transform + LAST-ARRIVER HEAD closer ------------
// 128 blocks = b(8) x seg(16), 128 threads. image 0 reads x2; b>=1 reads relu(h2+g2b).
// Last seg-block per image computes linear head + log_softmax (order-identical to the
// old head_kernel).
__global__ void pool_head(const float* __restrict__ x2, const float* __restrict__ h2,
                          const float* __restrict__ bias2, float* __restrict__ part,
                          const float* __restrict__ ow, const float* __restrict__ ob,
                          int* __restrict__ cntpool, float* __restrict__ out)
{
    __shared__ float pooled[128];
    __shared__ float logits[10];
    __shared__ int lastf;
    int b = blockIdx.x >> 4, seg = blockIdx.x & 15, t = threadIdx.x;
    float acc = 0.f;
    if (b == 0) {
        const float* p = x2 + ((size_t)seg * 64) * 128 + t;
#pragma unroll 8
        for (int n = 0; n < 64; ++n) acc += p[(size_t)n * 128];
    } else {
        float bz = bias2[t];
        const float* p = h2 + ((size_t)b * 1024 + seg * 64) * 128 + t;
#pragma unroll 8
        for (int n = 0; n < 64; ++n) acc += relu_f(p[(size_t)n * 128] + bz);
    }
    part[(b * 16 + seg) * 128 + t] = acc;

    __threadfence();
    __syncthreads();
    if (t == 0) lastf = (atomicAdd(&cntpool[b], 1) == 15);
    __syncthreads();
    if (lastf) {
        __threadfence();
        float s = 0.f;
#pragma unroll
        for (int sgi = 0; sgi < 16; ++sgi) s += part[(b * 16 + sgi) * 128 + t];
        pooled[t] = s * (1.f / 1024.f);
        __syncthreads();
        if (t < 10) {
            float l = ob[t];
            for (int c = 0; c < 128; ++c) l += pooled[c] * ow[c * 10 + t];
            logits[t] = l;
        }
        __syncthreads();
        if (t == 0) {
            float mx = logits[0];
            for (int j = 1; j < 10; ++j) mx = fmaxf(mx, logits[j]);
            float sum = 0.f;
            for (int j = 0; j < 10; ++j) sum += expf(logits[j] - mx);
            float lse = mx + logf(sum);
            for (int j = 0; j < 10; ++j) out[b * 10 + j] = logits[j] - lse;
        }
    }
}

extern "C" void kernel_launch(void* const* d_in, const int* in_sizes, int n_in,
                              void* d_out, int out_size, void* d_ws, size_t ws_size,
                              hipStream_t stream)
{
    const float* images = (const float*)d_in[0];
    const float* c1w = (const float*)d_in[1];
    const float* c1b = (const float*)d_in[2];
    const float* bn1g = (const float*)d_in[3];
    const float* bn1b = (const float*)d_in[4];
    const float* bn1m = (const float*)d_in[5];
    const float* bn1v = (const float*)d_in[6];
    const float* c2w = (const float*)d_in[7];
    const float* c2b = (const float*)d_in[8];
    const float* bn2g = (const float*)d_in[9];
    const float* bn2b = (const float*)d_in[10];
    const float* bn2m = (const float*)d_in[11];
    const float* bn2v = (const float*)d_in[12];
    const float* g1w = (const float*)d_in[13];
    const float* g1as = (const float*)d_in[14];
    const float* g1ad = (const float*)d_in[15];
    const float* g1b = (const float*)d_in[16];
    const float* g2w = (const float*)d_in[17];
    const float* g2as = (const float*)d_in[18];
    const float* g2ad = (const float*)d_in[19];
    const float* g2b = (const float*)d_in[20];
    const float* ow = (const float*)d_in[21];
    const float* ob = (const float*)d_in[22];
    float* out = (float*)d_out;

    // ws layout (floats):
    //   ws+0        (2M): c2p planes (K2-K3) -> x1 (written by K4 closers, read K5)
    //   ws+2097152  (512K): bufc1 (K1-K2) -> part/pden1/pden2 after K2
    //   ws+2621440  (2M): h1 (K3-K5) -> pacc2 (K6)            [h1 dead after K5]
    //   ws+4718592  (1M): pacc1 (K4) -> x2 (K6 closers, K7)   [pacc1 dead after K4]
    //   ws+5767168  (1M): h2 (K5-K7)
    //   ws+6815744+ : sp1,dp1,sp2,dp2, closer counters (ints)
    float* ws = (float*)d_ws;
    float* c2p   = ws;                    // 2,097,152
    float* x1    = ws;                    // 1024 x 256 (over dead c2p)
    float* bufc1 = ws + 2097152;          //   524,288
    float* h1    = ws + 2621440;          // 2,097,152
    float* pacc1 = ws + 4718592;          // 4*1024*256 = 1,048,576
    float* x2    = ws + 4718592;          // 1024 x 128 (over dead pacc1)
    float* h2    = ws + 5767168;          // 1,048,576
    float* sp1   = ws + 6815744;          // 4 x 1024
    float* dp1   = ws + 6819840;          // 4 x 1024
    float* sp2   = ws + 6823936;          // 2 x 1024
    float* dp2   = ws + 6825984;          // 2 x 1024
    int*   cnts  = (int*)(ws + 6828032);  // 200 ints: tilecnt1[128], tilecnt2[64], cntpool[8]
    int*   tilecnt1 = cnts;
    int*   tilecnt2 = cnts + 128;
    int*   cntpool  = cnts + 192;
    float* part  = bufc1;                 // 16,384 floats (bufc1 dead after K2)
    float* pden1 = bufc1 + 16384;         // 4 x 1024
    float* pden2 = bufc1 + 24576;         // 8 x 1024
    float* pacc2 = h1;                    // 8*1024*128 = 1,048,576 (h1 dead after K5)

    conv1_pool<<<512, 256, 0, stream>>>(images, c1w, c1b, bn1g, bn1b, bn1m, bn1v,
                                        bufc1, cnts);
    conv2_split<<<1024, 256, 0, stream>>>(bufc1, c2w, c2p);

    gemm1_planes<<<dim3(256, 4), 256, 0, stream>>>(
        c2p, c2b, bn2g, bn2b, bn2m, bn2v, g1w, h1, g1as, g1ad, sp1, dp1);
    gat_agg_gemm<256, 4, 4><<<dim3(32, 4, 4), 256, 0, stream>>>(
        h1, sp1, dp1, pacc1, pden1, g1b, x1, tilecnt1);

    gemm32<256, 128, true, true><<<dim3(256, 2), 256, 0, stream>>>(
        x1, h1, g1b, g2w, h2, g2as, g2ad, sp2, dp2);
    gat_agg_gemm<128, 8, 2><<<dim3(32, 2, 8), 256, 0, stream>>>(
        h2, sp2, dp2, pacc2, pden2, g2b, x2, tilecnt2);

    pool_head<<<128, 128, 0, stream>>>(x2, h2, g2b, part, ow, ob, cntpool, out);
}

// Round 11
// 217.586 us; speedup vs baseline: 1.4225x; 1.4225x over previous
//
#include <hip/hip_runtime.h>
#include <math.h>

#define BN_EPS 1e-5f
#define NEG_SLOPE 0.2f

__device__ __forceinline__ float relu_f(float x) { return x > 0.f ? x : 0.f; }
__device__ __forceinline__ float leaky_f(float z) { return z > 0.f ? z : NEG_SLOPE * z; }

// ---------------- conv1 (3->64, 3x3 SAME) fused bias+BN+ReLU+2x2maxpool ----------------
// grid 512 = b(8) x cog(16) x q(4); 256 threads = one pooled position, 4 co
__global__ void conv1_pool(const float* __restrict__ img, const float* __restrict__ w,
                           const float* __restrict__ cb, const float* __restrict__ g,
                           const float* __restrict__ bb, const float* __restrict__ m,
                           const float* __restrict__ vv, float* __restrict__ out)
{
    int blk = blockIdx.x;
    int q = blk & 3, cog = (blk >> 2) & 15, b = blk >> 6;
    int t = threadIdx.x;
    int x = t & 31, y = (q << 3) + (t >> 5);

    float acc[4][4] = {};
#pragma unroll
    for (int ci = 0; ci < 3; ++ci) {
        const float* ib = img + (b * 3 + ci) * 4096;
        float rv[4][4];
#pragma unroll
        for (int r = 0; r < 4; ++r) {
            int yy = 2 * y - 1 + r;
            bool yok = (unsigned)yy < 64u;
            const float* p = ib + yy * 64 + 2 * x;
            float2 c01 = yok ? *(const float2*)p : make_float2(0.f, 0.f);
            rv[r][1] = c01.x;
            rv[r][2] = c01.y;
            rv[r][0] = (yok && x > 0) ? p[-1] : 0.f;
            rv[r][3] = (yok && x < 31) ? p[2] : 0.f;
        }
#pragma unroll
        for (int j = 0; j < 4; ++j) {
            const float* wj = w + ((cog * 4 + j) * 3 + ci) * 9;
#pragma unroll
            for (int ky = 0; ky < 3; ++ky)
#pragma unroll
                for (int kx = 0; kx < 3; ++kx) {
                    float wvv = wj[ky * 3 + kx];
#pragma unroll
                    for (int py = 0; py < 2; ++py)
#pragma unroll
                        for (int px = 0; px < 2; ++px)
                            acc[j][py * 2 + px] += rv[py + ky][px + kx] * wvv;
                }
        }
    }
#pragma unroll
    for (int j = 0; j < 4; ++j) {
        int co = cog * 4 + j;
        float inv = g[co] / sqrtf(vv[co] + BN_EPS);
        float sh = cb[co] * inv + (bb[co] - m[co] * inv);
        float v0 = relu_f(acc[j][0] * inv + sh);
        float v1 = relu_f(acc[j][1] * inv + sh);
        float v2 = relu_f(acc[j][2] * inv + sh);
        float v3 = relu_f(acc[j][3] * inv + sh);
        out[((b * 64 + co) * 32 + y) * 32 + x] = fmaxf(fmaxf(v0, v1), fmaxf(v2, v3));
    }
}

// ---------------- conv2: 64->128, 3x3 SAME, SPLIT-K over ci (2 ways) ----------------
// grid 1024 = b(8) x cog(32) x half(2) x kz(2); 256 threads; each block reduces 32 ci.
// Partials BLOCK-LINEAR (fully coalesced): plane[kz] at ((bid*256+t)*8), bid=b*64+cog*2+half
__global__ void conv2_split(const float* __restrict__ in, const float* __restrict__ w,
                            float* __restrict__ c2p)
{
    int blk = blockIdx.x;
    int kz = blk & 1, half = (blk >> 1) & 1, cog = (blk >> 2) & 31, b = blk >> 7;
    int t = threadIdx.x;
    int x2p = (t & 15) * 2;
    int y = half * 16 + (t >> 4);
    bool xnz = x2p != 0;
    bool xhi = x2p == 30;
    const float* ibase = in + b * 65536 + kz * 32768;
    int xb = xnz ? x2p - 1 : 0;

    float acc[4][2] = {};

#pragma unroll 2
    for (int ci = 0; ci < 32; ++ci) {
        const float* cb2 = ibase + ci * 1024;
        float rc[3][4];
#pragma unroll
        for (int r = 0; r < 3; ++r) {
            int yy = y - 1 + r;
            bool yok = (unsigned)yy < 32u;
            const float* p = cb2 + yy * 32 + xb;
            float4 f = yok ? *(const float4*)p : make_float4(0.f, 0.f, 0.f, 0.f);
            rc[r][0] = xnz ? f.x : 0.f;
            rc[r][1] = xnz ? f.y : f.x;
            rc[r][2] = xnz ? f.z : f.y;
            float r3 = xnz ? f.w : f.z;
            rc[r][3] = xhi ? 0.f : r3;
        }
#pragma unroll
        for (int j = 0; j < 4; ++j) {
            const float* wj = w + ((cog * 4 + j) * 64 + kz * 32 + ci) * 9;
#pragma unroll
            for (int ky = 0; ky < 3; ++ky)
#pragma unroll
                for (int kx = 0; kx < 3; ++kx) {
                    float wvv = wj[ky * 3 + kx];
                    acc[j][0] += rc[ky][kx] * wvv;
                    acc[j][1] += rc[ky][kx + 1] * wvv;
                }
        }
    }

    float* pp = c2p + (size_t)kz * 1048576;
    int bid = b * 64 + cog * 2 + half;
    size_t base = ((size_t)bid * 256 + t) * 8;
    float4 s0 = {acc[0][0], acc[1][0], acc[2][0], acc[3][0]};
    float4 s1 = {acc[0][1], acc[1][1], acc[2][1], acc[3][1]};
    *(float4*)&pp[base] = s0;
    *(float4*)&pp[base + 4] = s1;
}

// ---------------- gemm1: h1 = relu(BN(plane0+plane1)) @ g1w — PANEL-RESIDENT ----------
// Full 128-deep A (fused conv2-combine, uniform across blocks) and B panel staged in LDS
// once; ONE barrier; 128-k inner loop with ZERO barriers.
// grid (256, 4), 256 threads; 32x64 tile, 2x4 micro; score epilogue for m0<1024.
__global__ void gemm1_planes(const float* __restrict__ c2p,
                             const float* __restrict__ cb, const float* __restrict__ g,
                             const float* __restrict__ bb, const float* __restrict__ mbn,
                             const float* __restrict__ vv,
                             const float* __restrict__ B, float* __restrict__ C,
                             const float* __restrict__ asrc, const float* __restrict__ adst,
                             float* __restrict__ sp, float* __restrict__ dp)
{
    __shared__ float As[128][33];   // [k][node]
    __shared__ float Bs[128][64];   // [k][col]
    __shared__ float invs[128];
    __shared__ float shs[128];
    int t = threadIdx.x;
    if (t < 128) {
        float iv = g[t] / sqrtf(vv[t] + BN_EPS);
        invs[t] = iv;
        shs[t] = cb[t] * iv + (bb[t] - mbn[t] * iv);
    }

    int m0 = blockIdx.x * 32;
    int n0 = blockIdx.y * 64;
    int tx = t & 15, ty = t >> 4;
    int cg = t >> 6, u = t & 63;
    int xp = u >> 2, odd = (u >> 1) & 1, j0 = (u & 1) * 2;
    int node = 2 * xp + odd;
    int kloc = cg * 4 + j0;
    int b = m0 >> 10, y = (m0 >> 5) & 31;
    int half = y >> 4, yy = y & 15;
    size_t base = (size_t)(b * 64 + half) * 2048 + yy * 128 + cg * 4096 + 2 * u;
    const float* p0 = c2p + base;
    const float* p1 = c2p + 1048576 + base;
    __syncthreads();                          // invs/shs ready

#pragma unroll
    for (int k0 = 0; k0 < 128; k0 += 16) {
        float2 u0 = *(const float2*)&p0[(size_t)k0 * 1024];
        float2 u1 = *(const float2*)&p1[(size_t)k0 * 1024];
        int ch = k0 + kloc;
        As[ch][node] = relu_f((u0.x + u1.x) * invs[ch] + shs[ch]);
        As[ch + 1][node] = relu_f((u0.y + u1.y) * invs[ch + 1] + shs[ch + 1]);
        *(float4*)&Bs[k0 + ty][tx * 4] =
            *(const float4*)&B[(size_t)(k0 + ty) * 256 + n0 + tx * 4];
    }
    __syncthreads();                          // the only compute barrier

    float acc[2][4] = {};
#pragma unroll 8
    for (int k = 0; k < 128; ++k) {
        float a0 = As[k][ty * 2], a1 = As[k][ty * 2 + 1];
        float4 b4 = *(const float4*)&Bs[k][tx * 4];
        acc[0][0] += a0 * b4.x; acc[0][1] += a0 * b4.y;
        acc[0][2] += a0 * b4.z; acc[0][3] += a0 * b4.w;
        acc[1][0] += a1 * b4.x; acc[1][1] += a1 * b4.y;
        acc[1][2] += a1 * b4.z; acc[1][3] += a1 * b4.w;
    }
#pragma unroll
    for (int i = 0; i < 2; ++i) {
        float4 o = {acc[i][0], acc[i][1], acc[i][2], acc[i][3]};
        *(float4*)&C[(size_t)(m0 + ty * 2 + i) * 256 + n0 + tx * 4] = o;
    }

    if (m0 < 1024) {
        float4 as4 = *(const float4*)&asrc[n0 + tx * 4];
        float4 ad4 = *(const float4*)&adst[n0 + tx * 4];
#pragma unroll
        for (int i = 0; i < 2; ++i) {
            float ss = acc[i][0] * as4.x + acc[i][1] * as4.y +
                       acc[i][2] * as4.z + acc[i][3] * as4.w;
            float dd = acc[i][0] * ad4.x + acc[i][1] * ad4.y +
                       acc[i][2] * ad4.z + acc[i][3] * ad4.w;
#pragma unroll
            for (int off = 1; off < 16; off <<= 1) {
                ss += __shfl_xor(ss, off);
                dd += __shfl_xor(dd, off);
            }
            if (tx == 0) {
                sp[blockIdx.y * 1024 + m0 + ty * 2 + i] = ss;
                dp[blockIdx.y * 1024 + m0 + ty * 2 + i] = dd;
            }
        }
    }
}

// ---------------- gemm2: h2 = x1 @ g2w — PANEL-RESIDENT (2 panels of 128) ----------------
// rows >= 1024 read h1 and apply relu(a + b1) on load (fused self-loop path).
// 4 barriers total (vs 32); score epilogue for m0<1024.
__global__ void gemm2_sb(const float* __restrict__ A, const float* __restrict__ Ahi,
                         const float* __restrict__ abias,
                         const float* __restrict__ B, float* __restrict__ C,
                         const float* __restrict__ asrc, const float* __restrict__ adst,
                         float* __restrict__ sp, float* __restrict__ dp)
{
    __shared__ float As[128][33];
    __shared__ float Bs[128][64];
    int t = threadIdx.x;
    int m0 = blockIdx.x * 32;
    int n0 = blockIdx.y * 64;
    int tx = t & 15, ty = t >> 4;
    int am = t >> 3, ak2 = (t & 7) * 2;
    bool hi = m0 >= 1024;
    const float* Ab = hi ? Ahi : A;
    float acc[2][4] = {};

#pragma unroll
    for (int p = 0; p < 2; ++p) {
        if (p) __syncthreads();               // guard restaging
#pragma unroll
        for (int k0 = 0; k0 < 128; k0 += 16) {
            int kl = k0 + ak2, gk = p * 128 + kl;
            float2 av = *(const float2*)&Ab[(size_t)(m0 + am) * 256 + gk];
            if (hi) {
                av.x = relu_f(av.x + abias[gk]);
                av.y = relu_f(av.y + abias[gk + 1]);
            }
            As[kl][am] = av.x;
            As[kl + 1][am] = av.y;
            *(float4*)&Bs[k0 + ty][tx * 4] =
                *(const float4*)&B[(size_t)(p * 128 + k0 + ty) * 128 + n0 + tx * 4];
        }
        __syncthreads();
#pragma unroll 8
        for (int k = 0; k < 128; ++k) {
            float a0 = As[k][ty * 2], a1 = As[k][ty * 2 + 1];
            float4 b4 = *(const float4*)&Bs[k][tx * 4];
            acc[0][0] += a0 * b4.x; acc[0][1] += a0 * b4.y;
            acc[0][2] += a0 * b4.z; acc[0][3] += a0 * b4.w;
            acc[1][0] += a1 * b4.x; acc[1][1] += a1 * b4.y;
            acc[1][2] += a1 * b4.z; acc[1][3] += a1 * b4.w;
        }
    }
#pragma unroll
    for (int i = 0; i < 2; ++i) {
        float4 o = {acc[i][0], acc[i][1], acc[i][2], acc[i][3]};
        *(float4*)&C[(size_t)(m0 + ty * 2 + i) * 128 + n0 + tx * 4] = o;
    }

    if (m0 < 1024) {
        float4 as4 = *(const float4*)&asrc[n0 + tx * 4];
        float4 ad4 = *(const float4*)&adst[n0 + tx * 4];
#pragma unroll
        for (int i = 0; i < 2; ++i) {
            float ss = acc[i][0] * as4.x + acc[i][1] * as4.y +
                       acc[i][2] * as4.z + acc[i][3] * as4.w;
            float dd = acc[i][0] * ad4.x + acc[i][1] * ad4.y +
                       acc[i][2] * ad4.z + acc[i][3] * ad4.w;
#pragma unroll
            for (int off = 1; off < 16; off <<= 1) {
                ss += __shfl_xor(ss, off);
                dd += __shfl_xor(dd, off);
            }
            if (tx == 0) {
                sp[blockIdx.y * 1024 + m0 + ty * 2 + i] = ss;
                dp[blockIdx.y * 1024 + m0 + ty * 2 + i] = dd;
            }
        }
    }
}

// ---------------- GAT aggregation split-K — PANEL-RESIDENT, per-thread exp ----------------
// C[v,c] = sum_u exp(leaky(s[u]+d[v]) - m[v]) * h[u,c];  m[v] = leaky(smax + d[v])
// B (h-slice) staged in 128-deep panels; A values recomputed per-thread from Ss (no As
// LDS, no inner barriers). Denominator = per-thread sequential-k sum (deterministic).
// grid (32, D/64, KS), 256 threads.
template <int D, int KS, int NT>
__global__ void gat_agg_gemm(const float* __restrict__ h, const float* __restrict__ sp,
                             const float* __restrict__ dp, float* __restrict__ pacc,
                             float* __restrict__ pden)
{
    __shared__ float Ss[1024];
    __shared__ float Bs[128][64];
    __shared__ float red[4];

    const int CH = 1024 / KS;
    int t = threadIdx.x;
    int m0 = blockIdx.x * 32;
    int n0 = blockIdx.y * 64;
    int kz = blockIdx.z;
    int tx = t & 15, ty = t >> 4;
    int vg2 = tx * 2;

    // stage s (4 per thread, summing NT partials) + global max
    float4 sa = {0.f, 0.f, 0.f, 0.f};
#pragma unroll
    for (int nt = 0; nt < NT; ++nt) {
        float4 u = *(const float4*)&sp[nt * 1024 + t * 4];
        sa.x += u.x; sa.y += u.y; sa.z += u.z; sa.w += u.w;
    }
    *(float4*)&Ss[t * 4] = sa;
    float lm = fmaxf(fmaxf(sa.x, sa.y), fmaxf(sa.z, sa.w));
#pragma unroll
    for (int off = 1; off < 64; off <<= 1) lm = fmaxf(lm, __shfl_xor(lm, off));
    if ((t & 63) == 0) red[t >> 6] = lm;
    __syncthreads();
    float smax = fmaxf(fmaxf(red[0], red[1]), fmaxf(red[2], red[3]));

    float dv0 = 0.f, dv1 = 0.f;
#pragma unroll
    for (int nt = 0; nt < NT; ++nt) {
        dv0 += dp[nt * 1024 + m0 + vg2];
        dv1 += dp[nt * 1024 + m0 + vg2 + 1];
    }
    float mv0 = leaky_f(smax + dv0), mv1 = leaky_f(smax + dv1);
    float ds0 = 0.f, ds1 = 0.f;
    float acc[2][4] = {};

#pragma unroll
    for (int p = 0; p < CH / 128; ++p) {
        if (p) __syncthreads();               // guard restaging
        int kb = kz * CH + p * 128;
#pragma unroll
        for (int r0 = 0; r0 < 128; r0 += 16)
            *(float4*)&Bs[r0 + ty][tx * 4] =
                *(const float4*)&h[(size_t)(kb + r0 + ty) * D + n0 + tx * 4];
        __syncthreads();
#pragma unroll 4
        for (int k = 0; k < 128; ++k) {
            float su = Ss[kb + k];
            float a0 = __expf(leaky_f(su + dv0) - mv0);
            float a1 = __expf(leaky_f(su + dv1) - mv1);
            ds0 += a0; ds1 += a1;
            float4 b4 = *(const float4*)&Bs[k][tx * 4];
            acc[0][0] += a0 * b4.x; acc[0][1] += a0 * b4.y;
            acc[0][2] += a0 * b4.z; acc[0][3] += a0 * b4.w;
            acc[1][0] += a1 * b4.x; acc[1][1] += a1 * b4.y;
            acc[1][2] += a1 * b4.z; acc[1][3] += a1 * b4.w;
        }
    }

#pragma unroll
    for (int i = 0; i < 2; ++i) {
        float4 o = {acc[i][0], acc[i][1], acc[i][2], acc[i][3]};
        *(float4*)&pacc[((size_t)kz * 1024 + m0 + ty * 2 + i) * D + n0 + tx * 4] = o;
    }
    if (tx == 0) {
        pden[kz * 1024 + m0 + ty * 2] = ds0;      // identical across tx; benign
        pden[kz * 1024 + m0 + ty * 2 + 1] = ds1;  // redundant across n0-blocks: same value
    }
}

// combine split-K partials: out[v,c] = relu(sum_ks pacc / sum_ks pden + bias), v < 1024
template <int D, int KS>
__global__ void gat_combine(const float* __restrict__ pacc, const float* __restrict__ pden,
                            const float* __restrict__ bias, float* __restrict__ out)
{
    int idx = blockIdx.x * blockDim.x + threadIdx.x;
    if (idx >= 1024 * D / 4) return;
    int c4 = idx & (D / 4 - 1);
    int v = idx / (D / 4);
    float4 a = {0.f, 0.f, 0.f, 0.f};
    float den = 0.f;
#pragma unroll
    for (int ks = 0; ks < KS; ++ks) {
        float4 p = ((const float4*)pacc)[(size_t)(ks * 1024 + v) * (D / 4) + c4];
        a.x += p.x; a.y += p.y; a.z += p.z; a.w += p.w;
        den += pden[ks * 1024 + v];
    }
    float rd = 1.f / den;
    float4 bz = ((const float4*)bias)[c4];
    float4 o = {relu_f(a.x * rd + bz.x), relu_f(a.y * rd + bz.y),
                relu_f(a.z * rd + bz.z), relu_f(a.w * rd + bz.w)};
    ((float4*)out)[(size_t)v * (D / 4) + c4] = o;
}

// ---------------- mean-pool stage 1 (fused self-transform): 128 blocks, each sums 64 rows ----
// image 0 reads x2 (already relu'd); images 1..7 read relu(h2 + g2b) on the fly
__global__ void pool_part(const float* __restrict__ x2, const float* __restrict__ h2,
                          const float* __restrict__ bias2, float* __restrict__ part)
{
    int b = blockIdx.x >> 4, seg = blockIdx.x & 15, t = threadIdx.x;
    float acc = 0.f;
    if (b == 0) {
        const float* p = x2 + ((size_t)seg * 64) * 128 + t;
#pragma unroll 8
        for (int n = 0; n < 64; ++n) acc += p[(size_t)n * 128];
    } else {
        float bz = bias2[t];
        const float* p = h2 + ((size_t)b * 1024 + seg * 64) * 128 + t;
#pragma unroll 8
        for (int n = 0; n < 64; ++n) acc += relu_f(p[(size_t)n * 128] + bz);
    }
    part[(b * 16 + seg) * 128 + t] = acc;
}

// ---------------- head: reduce partials + linear + log_softmax ----------------
__global__ void head_kernel(const float* __restrict__ part, const float* __restrict__ ow,
                            const float* __restrict__ ob, float* __restrict__ out)
{
    __shared__ float pooled[128];
    __shared__ float logits[10];
    int b = blockIdx.x, t = threadIdx.x;
    float acc = 0.f;
#pragma unroll
    for (int sgi = 0; sgi < 16; ++sgi) acc += part[(b * 16 + sgi) * 128 + t];
    pooled[t] = acc * (1.f / 1024.f);
    __syncthreads();
    if (t < 10) {
        float l = ob[t];
        for (int c = 0; c < 128; ++c) l += pooled[c] * ow[c * 10 + t];
        logits[t] = l;
    }
    __syncthreads();
    if (t == 0) {
        float mx = logits[0];
        for (int j = 1; j < 10; ++j) mx = fmaxf(mx, logits[j]);
        float sum = 0.f;
        for (int j = 0; j < 10; ++j) sum += expf(logits[j] - mx);
        float lse = mx + logf(sum);
        for (int j = 0; j < 10; ++j) out[b * 10 + j] = logits[j] - lse;
    }
}

extern "C" void kernel_launch(void* const* d_in, const int* in_sizes, int n_in,
                              void* d_out, int out_size, void* d_ws, size_t ws_size,
                              hipStream_t stream)
{
    const float* images = (const float*)d_in[0];
    const float* c1w = (const float*)d_in[1];
    const float* c1b = (const float*)d_in[2];
    const float* bn1g = (const float*)d_in[3];
    const float* bn1b = (const float*)d_in[4];
    const float* bn1m = (const float*)d_in[5];
    const float* bn1v = (const float*)d_in[6];
    const float* c2w = (const float*)d_in[7];
    const float* c2b = (const float*)d_in[8];
    const float* bn2g = (const float*)d_in[9];
    const float* bn2b = (const float*)d_in[10];
    const float* bn2m = (const float*)d_in[11];
    const float* bn2v = (const float*)d_in[12];
    const float* g1w = (const float*)d_in[13];
    const float* g1as = (const float*)d_in[14];
    const float* g1ad = (const float*)d_in[15];
    const float* g1b = (const float*)d_in[16];
    const float* g2w = (const float*)d_in[17];
    const float* g2as = (const float*)d_in[18];
    const float* g2ad = (const float*)d_in[19];
    const float* g2b = (const float*)d_in[20];
    const float* ow = (const float*)d_in[21];
    const float* ob = (const float*)d_in[22];
    float* out = (float*)d_out;

    // ws layout (floats) — identical to R9 (all aliasing separated by kernel boundaries):
    //   ws+0        (2M): c2p planes (K2-K3) -> x1 (K5-K6)      [c2p dead after K3]
    //   ws+2097152  (512K): bufc1 (K1-K2) -> part/pden1/pden2 after K2
    //   ws+2621440  (2M): h1 (K3-K6) -> pacc2 (K7-K8)           [h1 dead after K6]
    //   ws+4718592  (1M): pacc1 (K4-K5) -> x2 (K8-K9)           [pacc1 dead after K5]
    //   ws+5767168  (1M): h2 (K6-K9)
    //   ws+6815744+ : sp1,dp1,sp2,dp2
    float* ws = (float*)d_ws;
    float* c2p   = ws;                    // 2,097,152
    float* x1    = ws;                    // 1024 x 256 (over dead c2p)
    float* bufc1 = ws + 2097152;          //   524,288
    float* h1    = ws + 2621440;          // 2,097,152
    float* pacc1 = ws + 4718592;          // 4*1024*256 = 1,048,576
    float* x2    = ws + 4718592;          // 1024 x 128 (over dead pacc1)
    float* h2    = ws + 5767168;          // 1,048,576
    float* sp1   = ws + 6815744;          // 4 x 1024
    float* dp1   = ws + 6819840;          // 4 x 1024
    float* sp2   = ws + 6823936;          // 2 x 1024
    float* dp2   = ws + 6825984;          // 2 x 1024
    float* part  = bufc1;                 // 16,384 floats (bufc1 dead after K2)
    float* pden1 = bufc1 + 16384;         // 4 x 1024
    float* pden2 = bufc1 + 24576;         // 8 x 1024
    float* pacc2 = h1;                    // 8*1024*128 = 1,048,576 (h1 dead after K6)

    conv1_pool<<<512, 256, 0, stream>>>(images, c1w, c1b, bn1g, bn1b, bn1m, bn1v, bufc1);
    conv2_split<<<1024, 256, 0, stream>>>(bufc1, c2w, c2p);

    gemm1_planes<<<dim3(256, 4), 256, 0, stream>>>(
        c2p, c2b, bn2g, bn2b, bn2m, bn2v, g1w, h1, g1as, g1ad, sp1, dp1);
    gat_agg_gemm<256, 4, 4><<<dim3(32, 4, 4), 256, 0, stream>>>(h1, sp1, dp1, pacc1, pden1);
    gat_combine<256, 4><<<256, 256, 0, stream>>>(pacc1, pden1, g1b, x1);

    gemm2_sb<<<dim3(256, 2), 256, 0, stream>>>(
        x1, h1, g1b, g2w, h2, g2as, g2ad, sp2, dp2);
    gat_agg_gemm<128, 8, 2><<<dim3(32, 2, 8), 256, 0, stream>>>(h2, sp2, dp2, pacc2, pden2);
    gat_combine<128, 8><<<128, 256, 0, stream>>>(pacc2, pden2, g2b, x2);

    pool_part<<<128, 128, 0, stream>>>(x2, h2, g2b, part);
    head_kernel<<<8, 128, 0, stream>>>(part, ow, ob, out);
}

// Round 12
// 203.393 us; speedup vs baseline: 1.5217x; 1.0698x over previous
//
#include <hip/hip_runtime.h>
#include <math.h>

#define BN_EPS 1e-5f
#define NEG_SLOPE 0.2f

__device__ __forceinline__ float relu_f(float x) { return x > 0.f ? x : 0.f; }
__device__ __forceinline__ float leaky_f(float z) { return z > 0.f ? z : NEG_SLOPE * z; }

// ---------------- conv1 (3->64, 3x3 SAME) fused bias+BN+ReLU+2x2maxpool ----------------
// grid 512 = b(8) x cog(16) x q(4); 256 threads = one pooled position, 4 co
__global__ void conv1_pool(const float* __restrict__ img, const float* __restrict__ w,
                           const float* __restrict__ cb, const float* __restrict__ g,
                           const float* __restrict__ bb, const float* __restrict__ m,
                           const float* __restrict__ vv, float* __restrict__ out)
{
    int blk = blockIdx.x;
    int q = blk & 3, cog = (blk >> 2) & 15, b = blk >> 6;
    int t = threadIdx.x;
    int x = t & 31, y = (q << 3) + (t >> 5);

    float acc[4][4] = {};
#pragma unroll
    for (int ci = 0; ci < 3; ++ci) {
        const float* ib = img + (b * 3 + ci) * 4096;
        float rv[4][4];
#pragma unroll
        for (int r = 0; r < 4; ++r) {
            int yy = 2 * y - 1 + r;
            bool yok = (unsigned)yy < 64u;
            const float* p = ib + yy * 64 + 2 * x;
            float2 c01 = yok ? *(const float2*)p : make_float2(0.f, 0.f);
            rv[r][1] = c01.x;
            rv[r][2] = c01.y;
            rv[r][0] = (yok && x > 0) ? p[-1] : 0.f;
            rv[r][3] = (yok && x < 31) ? p[2] : 0.f;
        }
#pragma unroll
        for (int j = 0; j < 4; ++j) {
            const float* wj = w + ((cog * 4 + j) * 3 + ci) * 9;
#pragma unroll
            for (int ky = 0; ky < 3; ++ky)
#pragma unroll
                for (int kx = 0; kx < 3; ++kx) {
                    float wvv = wj[ky * 3 + kx];
#pragma unroll
                    for (int py = 0; py < 2; ++py)
#pragma unroll
                        for (int px = 0; px < 2; ++px)
                            acc[j][py * 2 + px] += rv[py + ky][px + kx] * wvv;
                }
        }
    }
#pragma unroll
    for (int j = 0; j < 4; ++j) {
        int co = cog * 4 + j;
        float inv = g[co] / sqrtf(vv[co] + BN_EPS);
        float sh = cb[co] * inv + (bb[co] - m[co] * inv);
        float v0 = relu_f(acc[j][0] * inv + sh);
        float v1 = relu_f(acc[j][1] * inv + sh);
        float v2 = relu_f(acc[j][2] * inv + sh);
        float v3 = relu_f(acc[j][3] * inv + sh);
        out[((b * 64 + co) * 32 + y) * 32 + x] = fmaxf(fmaxf(v0, v1), fmaxf(v2, v3));
    }
}

// ---------------- conv2: 64->128, 3x3 SAME, SPLIT-K over ci (2 ways) ----------------
// grid 1024 = b(8) x cog(32) x half(2) x kz(2); 256 threads; each block reduces 32 ci.
// Partials BLOCK-LINEAR (fully coalesced): plane[kz] at ((bid*256+t)*8), bid=b*64+cog*2+half
// 8-float block layout per (bid,t): [x2p: ch cog*4+0..3][x2p+1: ch cog*4+0..3]
__global__ void conv2_split(const float* __restrict__ in, const float* __restrict__ w,
                            float* __restrict__ c2p)
{
    int blk = blockIdx.x;
    int kz = blk & 1, half = (blk >> 1) & 1, cog = (blk >> 2) & 31, b = blk >> 7;
    int t = threadIdx.x;
    int x2p = (t & 15) * 2;
    int y = half * 16 + (t >> 4);
    bool xnz = x2p != 0;
    bool xhi = x2p == 30;
    const float* ibase = in + b * 65536 + kz * 32768;
    int xb = xnz ? x2p - 1 : 0;

    float acc[4][2] = {};

#pragma unroll 2
    for (int ci = 0; ci < 32; ++ci) {
        const float* cb2 = ibase + ci * 1024;
        float rc[3][4];
#pragma unroll
        for (int r = 0; r < 3; ++r) {
            int yy = y - 1 + r;
            bool yok = (unsigned)yy < 32u;
            const float* p = cb2 + yy * 32 + xb;
            float4 f = yok ? *(const float4*)p : make_float4(0.f, 0.f, 0.f, 0.f);
            rc[r][0] = xnz ? f.x : 0.f;
            rc[r][1] = xnz ? f.y : f.x;
            rc[r][2] = xnz ? f.z : f.y;
            float r3 = xnz ? f.w : f.z;
            rc[r][3] = xhi ? 0.f : r3;
        }
#pragma unroll
        for (int j = 0; j < 4; ++j) {
            const float* wj = w + ((cog * 4 + j) * 64 + kz * 32 + ci) * 9;
#pragma unroll
            for (int ky = 0; ky < 3; ++ky)
#pragma unroll
                for (int kx = 0; kx < 3; ++kx) {
                    float wvv = wj[ky * 3 + kx];
                    acc[j][0] += rc[ky][kx] * wvv;
                    acc[j][1] += rc[ky][kx + 1] * wvv;
                }
        }
    }

    float* pp = c2p + (size_t)kz * 1048576;
    int bid = b * 64 + cog * 2 + half;
    size_t base = ((size_t)bid * 256 + t) * 8;
    float4 s0 = {acc[0][0], acc[1][0], acc[2][0], acc[3][0]};
    float4 s1 = {acc[0][1], acc[1][1], acc[2][1], acc[3][1]};
    *(float4*)&pp[base] = s0;
    *(float4*)&pp[base + 4] = s1;
}

// ---------------- gemm1: h1 = relu(BN(plane0+plane1)) @ g1w, conv2-combine FUSED ----------
// A consumed directly from the block-linear conv2 planes — uniform across all blocks.
// grid (256, 4), 256 threads; 32x64 tile, 2x4 micro; score epilogue for m0<1024.
__global__ void gemm1_planes(const float* __restrict__ c2p,
                             const float* __restrict__ cb, const float* __restrict__ g,
                             const float* __restrict__ bb, const float* __restrict__ mbn,
                             const float* __restrict__ vv,
                             const float* __restrict__ B, float* __restrict__ C,
                             const float* __restrict__ asrc, const float* __restrict__ adst,
                             float* __restrict__ sp, float* __restrict__ dp)
{
    __shared__ float As[16][33];
    __shared__ float Bs[16][64];
    __shared__ float invs[128];
    __shared__ float shs[128];
    int t = threadIdx.x;
    if (t < 128) {
        float iv = g[t] / sqrtf(vv[t] + BN_EPS);
        invs[t] = iv;
        shs[t] = cb[t] * iv + (bb[t] - mbn[t] * iv);
    }

    int m0 = blockIdx.x * 32;
    int n0 = blockIdx.y * 64;
    int tx = t & 15, ty = t >> 4;
    int cg = t >> 6, u = t & 63;
    int xp = u >> 2, odd = (u >> 1) & 1, j0 = (u & 1) * 2;
    int node = 2 * xp + odd;
    int kloc = cg * 4 + j0;
    int b = m0 >> 10, y = (m0 >> 5) & 31;
    int half = y >> 4, yy = y & 15;
    size_t base = (size_t)(b * 64 + half) * 2048 + yy * 128 + cg * 4096 + 2 * u;
    const float* p0 = c2p + base;
    const float* p1 = c2p + 1048576 + base;
    __syncthreads();

    float acc[2][4] = {};
    for (int k0 = 0; k0 < 128; k0 += 16) {
        float2 u0 = *(const float2*)&p0[(size_t)k0 * 1024];
        float2 u1 = *(const float2*)&p1[(size_t)k0 * 1024];
        int ch = k0 + kloc;
        float avx = relu_f((u0.x + u1.x) * invs[ch] + shs[ch]);
        float avy = relu_f((u0.y + u1.y) * invs[ch + 1] + shs[ch + 1]);
        float4 bv = *(const float4*)&B[(size_t)(k0 + ty) * 256 + n0 + tx * 4];
        __syncthreads();
        As[kloc][node] = avx;
        As[kloc + 1][node] = avy;
        *(float4*)&Bs[ty][tx * 4] = bv;
        __syncthreads();
#pragma unroll
        for (int kk = 0; kk < 16; ++kk) {
            float a0 = As[kk][ty * 2], a1 = As[kk][ty * 2 + 1];
            float4 b4 = *(const float4*)&Bs[kk][tx * 4];
            acc[0][0] += a0 * b4.x; acc[0][1] += a0 * b4.y;
            acc[0][2] += a0 * b4.z; acc[0][3] += a0 * b4.w;
            acc[1][0] += a1 * b4.x; acc[1][1] += a1 * b4.y;
            acc[1][2] += a1 * b4.z; acc[1][3] += a1 * b4.w;
        }
    }
#pragma unroll
    for (int i = 0; i < 2; ++i) {
        float4 o = {acc[i][0], acc[i][1], acc[i][2], acc[i][3]};
        *(float4*)&C[(size_t)(m0 + ty * 2 + i) * 256 + n0 + tx * 4] = o;
    }

    if (m0 < 1024) {
        float4 as4 = *(const float4*)&asrc[n0 + tx * 4];
        float4 ad4 = *(const float4*)&adst[n0 + tx * 4];
#pragma unroll
        for (int i = 0; i < 2; ++i) {
            float ss = acc[i][0] * as4.x + acc[i][1] * as4.y +
                       acc[i][2] * as4.z + acc[i][3] * as4.w;
            float dd = acc[i][0] * ad4.x + acc[i][1] * ad4.y +
                       acc[i][2] * ad4.z + acc[i][3] * ad4.w;
#pragma unroll
            for (int off = 1; off < 16; off <<= 1) {
                ss += __shfl_xor(ss, off);
                dd += __shfl_xor(dd, off);
            }
            if (tx == 0) {
                sp[blockIdx.y * 1024 + m0 + ty * 2 + i] = ss;
                dp[blockIdx.y * 1024 + m0 + ty * 2 + i] = dd;
            }
        }
    }
}

// ---------------- tiled GEMM (gemm2): 32x64 tile, 256 threads, 2x4 micro ----------------
// SELF: rows >= 1024 read Ahi and apply relu(a + abias) on load (fused self-loop path).
// SCORE: blocks with m0<1024 emit per-n-tile partial attention scores.
template <int K, int N, bool SELF, bool SCORE>
__global__ void gemm32(const float* __restrict__ A, const float* __restrict__ Ahi,
                       const float* __restrict__ abias,
                       const float* __restrict__ B, float* __restrict__ C,
                       const float* __restrict__ asrc, const float* __restrict__ adst,
                       float* __restrict__ sp, float* __restrict__ dp)
{
    __shared__ float As[16][33];
    __shared__ float Bs[16][64];
    int t = threadIdx.x;
    int m0 = blockIdx.x * 32;
    int n0 = blockIdx.y * 64;
    int tx = t & 15, ty = t >> 4;
    int am = t >> 3, ak2 = (t & 7) * 2;
    bool hi = SELF && m0 >= 1024;
    const float* Ab = hi ? Ahi : A;
    float acc[2][4] = {};

    for (int k0 = 0; k0 < K; k0 += 16) {
        float2 av = *(const float2*)&Ab[(size_t)(m0 + am) * K + k0 + ak2];
        if (hi) {
            av.x = relu_f(av.x + abias[k0 + ak2]);
            av.y = relu_f(av.y + abias[k0 + ak2 + 1]);
        }
        float4 bv = *(const float4*)&B[(size_t)(k0 + ty) * N + n0 + tx * 4];
        __syncthreads();
        As[ak2][am] = av.x;
        As[ak2 + 1][am] = av.y;
        *(float4*)&Bs[ty][tx * 4] = bv;
        __syncthreads();
#pragma unroll
        for (int kk = 0; kk < 16; ++kk) {
            float a0 = As[kk][ty * 2], a1 = As[kk][ty * 2 + 1];
            float4 b4 = *(const float4*)&Bs[kk][tx * 4];
            acc[0][0] += a0 * b4.x; acc[0][1] += a0 * b4.y;
            acc[0][2] += a0 * b4.z; acc[0][3] += a0 * b4.w;
            acc[1][0] += a1 * b4.x; acc[1][1] += a1 * b4.y;
            acc[1][2] += a1 * b4.z; acc[1][3] += a1 * b4.w;
        }
    }
#pragma unroll
    for (int i = 0; i < 2; ++i) {
        float4 o = {acc[i][0], acc[i][1], acc[i][2], acc[i][3]};
        *(float4*)&C[(size_t)(m0 + ty * 2 + i) * N + n0 + tx * 4] = o;
    }

    if (SCORE && m0 < 1024) {
        float4 as4 = *(const float4*)&asrc[n0 + tx * 4];
        float4 ad4 = *(const float4*)&adst[n0 + tx * 4];
#pragma unroll
        for (int i = 0; i < 2; ++i) {
            float ss = acc[i][0] * as4.x + acc[i][1] * as4.y +
                       acc[i][2] * as4.z + acc[i][3] * as4.w;
            float dd = acc[i][0] * ad4.x + acc[i][1] * ad4.y +
                       acc[i][2] * ad4.z + acc[i][3] * ad4.w;
#pragma unroll
            for (int off = 1; off < 16; off <<= 1) {
                ss += __shfl_xor(ss, off);
                dd += __shfl_xor(dd, off);
            }
            if (tx == 0) {
                sp[blockIdx.y * 1024 + m0 + ty * 2 + i] = ss;
                dp[blockIdx.y * 1024 + m0 + ty * 2 + i] = dd;
            }
        }
    }
}

// ---------------- GAT aggregation split-K GEMM, 32x64 tile, 256 threads (4 waves) ----------
// C[v,c] = sum_u exp(leaky(s[u]+d[v]) - m[v]) * h[u,c];  m[v] = leaky(smax + d[v])
// s/d come as NT per-n-tile partials (sp[nt*1024+u]); summed at staging (deterministic).
// grid (32, D/64, KS)
template <int D, int KS, int NT>
__global__ void gat_agg_gemm(const float* __restrict__ h, const float* __restrict__ sp,
                             const float* __restrict__ dp, float* __restrict__ pacc,
                             float* __restrict__ pden)
{
    __shared__ float Ss[1024];
    __shared__ float As[16][33];
    __shared__ float Bs[16][64];
    __shared__ float red[4];
    __shared__ float part[16][32];

    const int CH = 1024 / KS;
    int t = threadIdx.x;
    int m0 = blockIdx.x * 32;
    int n0 = blockIdx.y * 64;
    int kz = blockIdx.z;
    int tx = t & 15, ty = t >> 4;
    int vg2 = tx * 2;                      // A-gen: u-row=ty, v-cols vg2,vg2+1

    // stage s (4 per thread, summing NT partials) + global max
    float4 sa = {0.f, 0.f, 0.f, 0.f};
#pragma unroll
    for (int nt = 0; nt < NT; ++nt) {
        float4 u = *(const float4*)&sp[nt * 1024 + t * 4];
        sa.x += u.x; sa.y += u.y; sa.z += u.z; sa.w += u.w;
    }
    *(float4*)&Ss[t * 4] = sa;
    float lm = fmaxf(fmaxf(sa.x, sa.y), fmaxf(sa.z, sa.w));
#pragma unroll
    for (int off = 1; off < 64; off <<= 1) lm = fmaxf(lm, __shfl_xor(lm, off));
    if ((t & 63) == 0) red[t >> 6] = lm;
    __syncthreads();
    float smax = fmaxf(fmaxf(red[0], red[1]), fmaxf(red[2], red[3]));

    float dv0 = 0.f, dv1 = 0.f;
#pragma unroll
    for (int nt = 0; nt < NT; ++nt) {
        dv0 += dp[nt * 1024 + m0 + vg2];
        dv1 += dp[nt * 1024 + m0 + vg2 + 1];
    }
    float mv0 = leaky_f(smax + dv0), mv1 = leaky_f(smax + dv1);
    float ds0 = 0.f, ds1 = 0.f;
    float acc[2][4] = {};

    for (int k0 = kz * CH; k0 < kz * CH + CH; k0 += 16) {
        float4 bv = *(const float4*)&h[(size_t)(k0 + ty) * D + n0 + tx * 4];
        float su = Ss[k0 + ty];
        float a0 = __expf(leaky_f(su + dv0) - mv0);
        float a1 = __expf(leaky_f(su + dv1) - mv1);
        ds0 += a0; ds1 += a1;
        __syncthreads();
        As[ty][vg2] = a0;
        As[ty][vg2 + 1] = a1;
        *(float4*)&Bs[ty][tx * 4] = bv;
        __syncthreads();
#pragma unroll
        for (int kk = 0; kk < 16; ++kk) {
            float a0m = As[kk][ty * 2], a1m = As[kk][ty * 2 + 1];
            float4 b4 = *(const float4*)&Bs[kk][tx * 4];
            acc[0][0] += a0m * b4.x; acc[0][1] += a0m * b4.y;
            acc[0][2] += a0m * b4.z; acc[0][3] += a0m * b4.w;
            acc[1][0] += a1m * b4.x; acc[1][1] += a1m * b4.y;
            acc[1][2] += a1m * b4.z; acc[1][3] += a1m * b4.w;
        }
    }

    __syncthreads();
    part[ty][vg2] = ds0;
    part[ty][vg2 + 1] = ds1;
    __syncthreads();

#pragma unroll
    for (int i = 0; i < 2; ++i) {
        float4 o = {acc[i][0], acc[i][1], acc[i][2], acc[i][3]};
        *(float4*)&pacc[((size_t)kz * 1024 + m0 + ty * 2 + i) * D + n0 + tx * 4] = o;
    }
    if (t < 32) {
        float den = 0.f;
#pragma unroll
        for (int u = 0; u < 16; ++u) den += part[u][t];
        pden[kz * 1024 + m0 + t] = den;   // redundant across n0-blocks: same value, benign
    }
}

// combine split-K partials: out[v,c] = relu(sum_ks pacc / sum_ks pden + bias), v < 1024
template <int D, int KS>
__global__ void gat_combine(const float* __restrict__ pacc, const float* __restrict__ pden,
                            const float* __restrict__ bias, float* __restrict__ out)
{
    int idx = blockIdx.x * blockDim.x + threadIdx.x;
    if (idx >= 1024 * D / 4) return;
    int c4 = idx & (D / 4 - 1);
    int v = idx / (D / 4);
    float4 a = {0.f, 0.f, 0.f, 0.f};
    float den = 0.f;
#pragma unroll
    for (int ks = 0; ks < KS; ++ks) {
        float4 p = ((const float4*)pacc)[(size_t)(ks * 1024 + v) * (D / 4) + c4];
        a.x += p.x; a.y += p.y; a.z += p.z; a.w += p.w;
        den += pden[ks * 1024 + v];
    }
    float rd = 1.f / den;
    float4 bz = ((const float4*)bias)[c4];
    float4 o = {relu_f(a.x * rd + bz.x), relu_f(a.y * rd + bz.y),
                relu_f(a.z * rd + bz.z), relu_f(a.w * rd + bz.w)};
    ((float4*)out)[(size_t)v * (D / 4) + c4] = o;
}

// ---------------- mean-pool stage 1 (fused self-transform): 128 blocks, each sums 64 rows ----
// image 0 reads x2 (already relu'd); images 1..7 read relu(h2 + g2b) on the fly
__global__ void pool_part(const float* __restrict__ x2, const float* __restrict__ h2,
                          const float* __restrict__ bias2, float* __restrict__ part)
{
    int b = blockIdx.x >> 4, seg = blockIdx.x & 15, t = threadIdx.x;
    float acc = 0.f;
    if (b == 0) {
        const float* p = x2 + ((size_t)seg * 64) * 128 + t;
#pragma unroll 8
        for (int n = 0; n < 64; ++n) acc += p[(size_t)n * 128];
    } else {
        float bz = bias2[t];
        const float* p = h2 + ((size_t)b * 1024 + seg * 64) * 128 + t;
#pragma unroll 8
        for (int n = 0; n < 64; ++n) acc += relu_f(p[(size_t)n * 128] + bz);
    }
    part[(b * 16 + seg) * 128 + t] = acc;
}

// ---------------- head: reduce partials + linear + log_softmax ----------------
__global__ void head_kernel(const float* __restrict__ part, const float* __restrict__ ow,
                            const float* __restrict__ ob, float* __restrict__ out)
{
    __shared__ float pooled[128];
    __shared__ float logits[10];
    int b = blockIdx.x, t = threadIdx.x;
    float acc = 0.f;
#pragma unroll
    for (int sgi = 0; sgi < 16; ++sgi) acc += part[(b * 16 + sgi) * 128 + t];
    pooled[t] = acc * (1.f / 1024.f);
    __syncthreads();
    if (t < 10) {
        float l = ob[t];
        for (int c = 0; c < 128; ++c) l += pooled[c] * ow[c * 10 + t];
        logits[t] = l;
    }
    __syncthreads();
    if (t == 0) {
        float mx = logits[0];
        for (int j = 1; j < 10; ++j) mx = fmaxf(mx, logits[j]);
        float sum = 0.f;
        for (int j = 0; j < 10; ++j) sum += expf(logits[j] - mx);
        float lse = mx + logf(sum);
        for (int j = 0; j < 10; ++j) out[b * 10 + j] = logits[j] - lse;
    }
}

extern "C" void kernel_launch(void* const* d_in, const int* in_sizes, int n_in,
                              void* d_out, int out_size, void* d_ws, size_t ws_size,
                              hipStream_t stream)
{
    const float* images = (const float*)d_in[0];
    const float* c1w = (const float*)d_in[1];
    const float* c1b = (const float*)d_in[2];
    const float* bn1g = (const float*)d_in[3];
    const float* bn1b = (const float*)d_in[4];
    const float* bn1m = (const float*)d_in[5];
    const float* bn1v = (const float*)d_in[6];
    const float* c2w = (const float*)d_in[7];
    const float* c2b = (const float*)d_in[8];
    const float* bn2g = (const float*)d_in[9];
    const float* bn2b = (const float*)d_in[10];
    const float* bn2m = (const float*)d_in[11];
    const float* bn2v = (const float*)d_in[12];
    const float* g1w = (const float*)d_in[13];
    const float* g1as = (const float*)d_in[14];
    const float* g1ad = (const float*)d_in[15];
    const float* g1b = (const float*)d_in[16];
    const float* g2w = (const float*)d_in[17];
    const float* g2as = (const float*)d_in[18];
    const float* g2ad = (const float*)d_in[19];
    const float* g2b = (const float*)d_in[20];
    const float* ow = (const float*)d_in[21];
    const float* ob = (const float*)d_in[22];
    float* out = (float*)d_out;

    // ws layout (floats):
    //   ws+0        (2M): c2p planes (K2-K3) -> x1 (K5-K6)      [c2p dead after K3]
    //   ws+2097152  (512K): bufc1 (K1-K2) -> part/pden1/pden2 after K2
    //   ws+2621440  (2M): h1 (K3-K6) -> pacc2 (K7-K8)           [h1 dead after K6]
    //   ws+4718592  (1M): pacc1 (K4-K5) -> x2 (K8-K9)           [pacc1 dead after K5]
    //   ws+5767168  (1M): h2 (K6-K9)
    //   ws+6815744+ : sp1,dp1,sp2,dp2
    float* ws = (float*)d_ws;
    float* c2p   = ws;                    // 2,097,152
    float* x1    = ws;                    // 1024 x 256 (over dead c2p)
    float* bufc1 = ws + 2097152;          //   524,288
    float* h1    = ws + 2621440;          // 2,097,152
    float* pacc1 = ws + 4718592;          // 4*1024*256 = 1,048,576
    float* x2    = ws + 4718592;          // 1024 x 128 (over dead pacc1)
    float* h2    = ws + 5767168;          // 1,048,576
    float* sp1   = ws + 6815744;          // 4 x 1024
    float* dp1   = ws + 6819840;          // 4 x 1024
    float* sp2   = ws + 6823936;          // 2 x 1024
    float* dp2   = ws + 6825984;          // 2 x 1024
    float* part  = bufc1;                 // 16,384 floats (bufc1 dead after K2)
    float* pden1 = bufc1 + 16384;         // 4 x 1024
    float* pden2 = bufc1 + 24576;         // 8 x 1024
    float* pacc2 = h1;                    // 8*1024*128 = 1,048,576 (h1 dead after K6)

    conv1_pool<<<512, 256, 0, stream>>>(images, c1w, c1b, bn1g, bn1b, bn1m, bn1v, bufc1);
    conv2_split<<<1024, 256, 0, stream>>>(bufc1, c2w, c2p);

    // gemm1 with conv2-combine fused into A-staging (uniform over all blocks) + scores
    gemm1_planes<<<dim3(256, 4), 256, 0, stream>>>(
        c2p, c2b, bn2g, bn2b, bn2m, bn2v, g1w, h1, g1as, g1ad, sp1, dp1);
    gat_agg_gemm<256, 4, 4><<<dim3(32, 4, 4), 256, 0, stream>>>(h1, sp1, dp1, pacc1, pden1);
    gat_combine<256, 4><<<256, 256, 0, stream>>>(pacc1, pden1, g1b, x1);

    // gemm2: rows<1024 from x1; rows>=1024 = relu(h1+g1b) fused; + score2 partials
    gemm32<256, 128, true, true><<<dim3(256, 2), 256, 0, stream>>>(
        x1, h1, g1b, g2w, h2, g2as, g2ad, sp2, dp2);
    gat_agg_gemm<128, 8, 2><<<dim3(32, 2, 8), 256, 0, stream>>>(h2, sp2, dp2, pacc2, pden2);
    gat_combine<128, 8><<<128, 256, 0, stream>>>(pacc2, pden2, g2b, x2);

    pool_part<<<128, 128, 0, stream>>>(x2, h2, g2b, part);
    head_kernel<<<8, 128, 0, stream>>>(part, ow, ob, out);
}